// Round 13
// baseline (3389.345 us; speedup 1.0000x reference)
//
#include <hip/hip_runtime.h>
#include <hip/hip_bf16.h>
#include <math.h>
#include <float.h>

#define NUM_CB 8
#define CB_SIZE 256
#define DIM 128
#define BT (16 * 16384)                  // 262144 tokens
#define Q_ELEMS ((size_t)BT * DIM)       // 33554432
#define I_ELEMS ((size_t)BT * NUM_CB)    // 2097152

#define TC 64                            // candidates per streamed tile
#define TILES_PER_CB (CB_SIZE / TC)      // 4
#define TILE_BYTES 32768                 // 2 planes x 64 cand x 16 slots x 16B

// Pass-A ambiguity margin (validated rounds 6-12). Do not shrink.
#define MARGIN_A 1.5e-4f

typedef short  bf16x8 __attribute__((ext_vector_type(8)));
typedef float  f32x4  __attribute__((ext_vector_type(4)));

__device__ __forceinline__ unsigned short bf16_rne(float f) {
    unsigned int u = __float_as_uint(f);
    u = u + 0x7FFFu + ((u >> 16) & 1u);
    return (unsigned short)(u >> 16);
}
__device__ __forceinline__ float bf16_tof(unsigned short h) {
    return __uint_as_float(((unsigned int)h) << 16);
}
// Fast HW split helpers (any deterministic split is covered by MARGIN_A).
__device__ __forceinline__ unsigned short f2bf(float f) {
    __hip_bfloat16 h = __float2bfloat16(f);
    return *reinterpret_cast<unsigned short*>(&h);
}

// ---------------------------------------------------------------------------
// VALIDATED np emulation (rounds 6-12): pairwise-8 sum-of-squares, no FMA.
// ---------------------------------------------------------------------------
__device__ __forceinline__ float np_sum_sq_128(const float* a) {
#pragma clang fp contract(off)
    float r0 = 0.f, r1 = 0.f, r2 = 0.f, r3 = 0.f,
          r4 = 0.f, r5 = 0.f, r6 = 0.f, r7 = 0.f;
#pragma unroll
    for (int i = 0; i < DIM; i += 8) {
        r0 = r0 + a[i + 0] * a[i + 0];
        r1 = r1 + a[i + 1] * a[i + 1];
        r2 = r2 + a[i + 2] * a[i + 2];
        r3 = r3 + a[i + 3] * a[i + 3];
        r4 = r4 + a[i + 4] * a[i + 4];
        r5 = r5 + a[i + 5] * a[i + 5];
        r6 = r6 + a[i + 6] * a[i + 6];
        r7 = r7 + a[i + 7] * a[i + 7];
    }
    return ((r0 + r1) + (r2 + r3)) + ((r4 + r5) + (r6 + r7));
}

__global__ void rvq_esq_kernel(const float* __restrict__ cb,
                               float* __restrict__ esq) {
    int i = blockIdx.x * blockDim.x + threadIdx.x;   // 0 .. 2047
    if (i >= NUM_CB * CB_SIZE) return;
    esq[i] = np_sum_sq_128(cb + (size_t)i * DIM);
}

// Transposed f32 codebook for coalesced Pass-B reads: cbT[k][d][c]
__global__ void rvq_transpose_kernel(const float* __restrict__ cb,
                                     float* __restrict__ cbT) {
    int idx = blockIdx.x * blockDim.x + threadIdx.x;   // 0 .. 262143
    if (idx >= NUM_CB * DIM * CB_SIZE) return;
    int c = idx & (CB_SIZE - 1);
    int d = (idx >> 8) & (DIM - 1);
    int k = idx >> 15;
    cbT[idx] = cb[((size_t)(k * CB_SIZE + c)) * DIM + d];
}

// ---------------------------------------------------------------------------
// Precompute merged bf16 hi|lo image in the swizzled LDS layout (validated):
// img[t*2048 + plane*1024 + cand*16 + (slot ^ (cand&15))], t = k*4 + T,
// codeword = t*64 + cand.
// ---------------------------------------------------------------------------
__global__ void rvq_split_kernel(const float* __restrict__ cb,
                                 bf16x8* __restrict__ g_img) {
    int idx = blockIdx.x * blockDim.x + threadIdx.x;   // 0 .. 32767
    if (idx >= NUM_CB * CB_SIZE * 16) return;
    int slot = idx & 15;
    int cand = (idx >> 4) & (TC - 1);
    int t    = idx >> 10;                 // 0..31
    const float* src = cb + ((size_t)t * TC + cand) * DIM + slot * 8;
    float4 a = *reinterpret_cast<const float4*>(src);
    float4 b = *reinterpret_cast<const float4*>(src + 4);
    float e[8] = {a.x, a.y, a.z, a.w, b.x, b.y, b.z, b.w};
    bf16x8 eh, el;
#pragma unroll
    for (int i = 0; i < 8; ++i) {
        unsigned short h = bf16_rne(e[i]);
        float rem = e[i] - bf16_tof(h);
        eh[i] = (short)h;
        el[i] = (short)bf16_rne(rem);
    }
    int ds = slot ^ (cand & 15);
    g_img[(size_t)t * 2048 + cand * 16 + ds]        = eh;
    g_img[(size_t)t * 2048 + 1024 + cand * 16 + ds] = el;
}

// DMA one 32KB tile into LDS buffer: 4 x global_load_lds(16B) per wave (8 wv).
__device__ __forceinline__ void stage_tile(const bf16x8* __restrict__ g_img,
                                           bf16x8 (*s_buf)[2048],
                                           int t, int nb, int wid, int lane) {
    const char* gt = (const char*)g_img + (size_t)t * TILE_BYTES
                     + wid * 4096 + lane * 16;
    const char* lb = (const char*)(&s_buf[nb][0]) + wid * 4096;  // wave-uniform
#pragma unroll
    for (int c = 0; c < 4; ++c) {
        __builtin_amdgcn_global_load_lds(
            (const __attribute__((address_space(1))) unsigned int*)(gt + c * 1024),
            (__attribute__((address_space(3))) unsigned int*)(lb + c * 1024),
            16, 0, 0);
    }
}

// ---------------------------------------------------------------------------
// Main fused kernel: 128 tokens/block (8 waves x 16), residual in VGPRs.
// SWAPPED MFMA: mfma(E, R) -> lane holds its OWN token's candidate scores
// (D col = token = lane&15, D row = candidate = 4*lq + j). Per-lane top-2,
// 2-step cross-lq reduce, no LDS selection traffic.
// ---------------------------------------------------------------------------
__global__ __launch_bounds__(512, 4) void rvq_mfma_kernel(
    const float* __restrict__ z,
    const float* __restrict__ cb,
    const float* __restrict__ cbT,
    const float* __restrict__ esq,
    const bf16x8* __restrict__ g_img,
    float* __restrict__ out_q,
    float* __restrict__ out_idx,
    double* __restrict__ loss_acc) {

    __shared__ bf16x8 s_buf[2][2048];                // 2 x 32KB double buffer
    __shared__ __align__(16) float s_rbuf[8][DIM];   // per-wave passB residual
    __shared__ double s_wsum[8];

    const int tid  = threadIdx.x;
    const int wid  = tid >> 6;
    const int lane = tid & 63;
    const int lrow = lane & 15;       // token-in-wave (B col / D col)
    const int lq   = lane >> 4;       // k-chunk group / D row group
    const int tokw = blockIdx.x * 128 + wid * 16;
    const int tok  = tokw + lrow;

    // ---- residual chunks: r[s][i] = z[tok][32s + 8lq + i] ----
    float r[4][8];
    {
        const float* zp = z + (size_t)tok * DIM + 8 * lq;
#pragma unroll
        for (int s = 0; s < 4; ++s) {
            float4 a = *reinterpret_cast<const float4*>(zp + 32 * s);
            float4 b = *reinterpret_cast<const float4*>(zp + 32 * s + 4);
            r[s][0] = a.x; r[s][1] = a.y; r[s][2] = a.z; r[s][3] = a.w;
            r[s][4] = b.x; r[s][5] = b.y; r[s][6] = b.z; r[s][7] = b.w;
        }
    }

    // ---- fast bf16 hi/mid split (HW RNE casts) ----
    bf16x8 ah[4], am[4];
#pragma unroll
    for (int s = 0; s < 4; ++s)
#pragma unroll
        for (int i = 0; i < 8; ++i) {
            unsigned short h = f2bf(r[s][i]);
            float rem = r[s][i] - bf16_tof(h);
            ah[s][i] = (short)h;
            am[s][i] = (short)f2bf(rem);
        }

    double lsum = 0.0;

    // prologue: stage tile 0
    stage_tile(g_img, s_buf, 0, 0, wid, lane);
    asm volatile("s_waitcnt vmcnt(0)" ::: "memory");
    __syncthreads();

    for (int k = 0; k < NUM_CB; ++k) {
        const float* esqk = esq + k * CB_SIZE;
        const float* cbk  = cb  + (size_t)k * CB_SIZE * DIM;
        const float* cbTk = cbT + (size_t)k * DIM * CB_SIZE + lane;

        float m1 = FLT_MAX, m2 = FLT_MAX;
        int   i1 = 0x7fffffff;

#pragma unroll
        for (int T = 0; T < TILES_PER_CB; ++T) {
            const int t  = k * TILES_PER_CB + T;
            const int nb = T & 1;
            if (k < NUM_CB - 1 || T < TILES_PER_CB - 1)
                stage_tile(g_img, s_buf, t + 1, nb ^ 1, wid, lane);

#pragma unroll
            for (int ctl = 0; ctl < 4; ++ctl) {   // 16-candidate column tiles
                const int ctg  = T * 4 + ctl;     // global ct 0..15
                const int base = (ctl * 16 + lrow) * 16;
                bf16x8 bh[4], bl[4];
#pragma unroll
                for (int s = 0; s < 4; ++s) {
                    int ls = (4 * s + lq) ^ lrow;
                    bh[s] = s_buf[nb][base + ls];
                    bl[s] = s_buf[nb][1024 + base + ls];
                }
                f32x4 acc0 = {0.f, 0.f, 0.f, 0.f};
                f32x4 acc1 = {0.f, 0.f, 0.f, 0.f};
                // SWAPPED: A = codebook frag, B = residual frag
                acc0 = __builtin_amdgcn_mfma_f32_16x16x32_bf16(bh[0], ah[0], acc0, 0, 0, 0);
                acc0 = __builtin_amdgcn_mfma_f32_16x16x32_bf16(bh[1], ah[1], acc0, 0, 0, 0);
                acc1 = __builtin_amdgcn_mfma_f32_16x16x32_bf16(bh[2], ah[2], acc1, 0, 0, 0);
                acc1 = __builtin_amdgcn_mfma_f32_16x16x32_bf16(bh[3], ah[3], acc1, 0, 0, 0);
                acc0 = __builtin_amdgcn_mfma_f32_16x16x32_bf16(bh[0], am[0], acc0, 0, 0, 0);
                acc0 = __builtin_amdgcn_mfma_f32_16x16x32_bf16(bh[1], am[1], acc0, 0, 0, 0);
                acc1 = __builtin_amdgcn_mfma_f32_16x16x32_bf16(bh[2], am[2], acc1, 0, 0, 0);
                acc1 = __builtin_amdgcn_mfma_f32_16x16x32_bf16(bh[3], am[3], acc1, 0, 0, 0);
                acc0 = __builtin_amdgcn_mfma_f32_16x16x32_bf16(bl[0], ah[0], acc0, 0, 0, 0);
                acc0 = __builtin_amdgcn_mfma_f32_16x16x32_bf16(bl[1], ah[1], acc0, 0, 0, 0);
                acc1 = __builtin_amdgcn_mfma_f32_16x16x32_bf16(bl[2], ah[2], acc1, 0, 0, 0);
                acc1 = __builtin_amdgcn_mfma_f32_16x16x32_bf16(bl[3], ah[3], acc1, 0, 0, 0);

                // scores: candidate c = ctg*16 + 4*lq + j for THIS lane's token
                float4 ev = *reinterpret_cast<const float4*>(
                    esqk + ctg * 16 + 4 * lq);
                const float es[4] = {ev.x, ev.y, ev.z, ev.w};
                const int cb0 = ctg * 16 + 4 * lq;
#pragma unroll
                for (int j = 0; j < 4; ++j) {
                    float s = fmaf(-2.0f, acc0[j] + acc1[j], es[j]);
                    m2 = fminf(m2, fmaxf(m1, s));
                    if (s < m1) { m1 = s; i1 = cb0 + j; }   // ascending c order
                }
            }

            if (T == TILES_PER_CB - 1) {
                // ============== per-codebook epilogue (wave-internal) ======
                // cross-lq top-2 lexicographic reduce (2 butterfly steps)
#pragma unroll
                for (int d = 16; d < 64; d <<= 1) {
                    float om1 = __shfl_xor(m1, d);
                    float om2 = __shfl_xor(m2, d);
                    int   oi1 = __shfl_xor(i1, d);
                    bool ow = (om1 < m1) || (om1 == m1 && oi1 < i1);
                    float lo = ow ? m1 : om1;
                    m1 = ow ? om1 : m1;
                    i1 = ow ? oi1 : i1;
                    m2 = fminf(fminf(m2, om2), lo);
                }
                int cmin = i1;

                // Pass B (rare): exact np argmin, coalesced cbT (validated)
                bool amb = !(m2 - m1 > MARGIN_A);
                unsigned long long mask = __ballot(amb && lane < 16);
                while (mask) {
                    int srct = __ffsll(mask) - 1;
                    mask &= mask - 1;
                    if (lrow == srct) {
#pragma unroll
                        for (int s = 0; s < 4; ++s) {
                            float4* dst = reinterpret_cast<float4*>(
                                &s_rbuf[wid][32 * s + 8 * lq]);
                            dst[0] = make_float4(r[s][0], r[s][1], r[s][2], r[s][3]);
                            dst[1] = make_float4(r[s][4], r[s][5], r[s][6], r[s][7]);
                        }
                    }
                    asm volatile("s_waitcnt lgkmcnt(0)" ::: "memory");
                    float xs = 0.f;
                    if (lane == 0) xs = np_sum_sq_128(&s_rbuf[wid][0]);
                    xs = __shfl(xs, 0);

                    const float* rb = &s_rbuf[wid][0];
                    float a0 = 0.f, a1 = 0.f, a2 = 0.f, a3 = 0.f;
#pragma unroll 8
                    for (int d = 0; d < DIM; ++d) {
                        float rv = rb[d];
                        const float* row = cbTk + (size_t)d * CB_SIZE;
                        a0 = fmaf(rv, row[0],   a0);
                        a1 = fmaf(rv, row[64],  a1);
                        a2 = fmaf(rv, row[128], a2);
                        a3 = fmaf(rv, row[192], a3);
                    }
                    float dd0, dd1, dd2, dd3;
                    {
#pragma clang fp contract(off)
                        float S0 = xs + esqk[lane];
                        float S1 = xs + esqk[lane + 64];
                        float S2 = xs + esqk[lane + 128];
                        float S3 = xs + esqk[lane + 192];
                        dd0 = S0 - 2.0f * a0;
                        dd1 = S1 - 2.0f * a1;
                        dd2 = S2 - 2.0f * a2;
                        dd3 = S3 - 2.0f * a3;
                    }
                    float bd = dd0; int bc = lane;
                    if (dd1 < bd) { bd = dd1; bc = lane + 64; }
                    if (dd2 < bd) { bd = dd2; bc = lane + 128; }
                    if (dd3 < bd) { bd = dd3; bc = lane + 192; }
#pragma unroll
                    for (int d = 1; d < 64; d <<= 1) {
                        float od = __shfl_xor(bd, d);
                        int   oc = __shfl_xor(bc, d);
                        if (od < bd || (od == bd && oc < bc)) { bd = od; bc = oc; }
                    }
                    if (lrow == srct) cmin = bc;   // all lanes have (bd,bc)
                }

                if (lane < 16)    // lane==lrow owner copy
                    out_idx[(size_t)(tokw + lane) * NUM_CB + k] = (float)cmin;

                // residual update + loss
                const float* ep = cbk + (size_t)cmin * DIM + 8 * lq;
                float l0 = 0.f, l1 = 0.f, l2 = 0.f, l3 = 0.f;
#pragma unroll
                for (int s = 0; s < 4; ++s) {
                    float4 ev0 = *reinterpret_cast<const float4*>(ep + 32 * s);
                    float4 ev1 = *reinterpret_cast<const float4*>(ep + 32 * s + 4);
                    float d0 = ev0.x - r[s][0], d1 = ev0.y - r[s][1];
                    float d2 = ev0.z - r[s][2], d3 = ev0.w - r[s][3];
                    float d4 = ev1.x - r[s][4], d5 = ev1.y - r[s][5];
                    float d6 = ev1.z - r[s][6], d7 = ev1.w - r[s][7];
                    l0 = fmaf(d0, d0, l0); l1 = fmaf(d1, d1, l1);
                    l2 = fmaf(d2, d2, l2); l3 = fmaf(d3, d3, l3);
                    l0 = fmaf(d4, d4, l0); l1 = fmaf(d5, d5, l1);
                    l2 = fmaf(d6, d6, l2); l3 = fmaf(d7, d7, l3);
                    r[s][0] -= ev0.x; r[s][1] -= ev0.y; r[s][2] -= ev0.z; r[s][3] -= ev0.w;
                    r[s][4] -= ev1.x; r[s][5] -= ev1.y; r[s][6] -= ev1.z; r[s][7] -= ev1.w;
                }
                lsum += (double)((l0 + l1) + (l2 + l3));

                if (k < NUM_CB - 1) {   // fast re-split for next codebook
#pragma unroll
                    for (int s = 0; s < 4; ++s)
#pragma unroll
                        for (int i = 0; i < 8; ++i) {
                            unsigned short h = f2bf(r[s][i]);
                            float rem = r[s][i] - bf16_tof(h);
                            ah[s][i] = (short)h;
                            am[s][i] = (short)f2bf(rem);
                        }
                }
                // ============== end epilogue ===============================
            }

            asm volatile("s_waitcnt vmcnt(0)" ::: "memory");  // prefetch landed
            __syncthreads();                                  // buf[nb] free
        }
    }

    // ---- quantized = z - r_final ----
    {
        const float* zp = z + (size_t)tok * DIM + 8 * lq;
        float* op = out_q + (size_t)tok * DIM + 8 * lq;
#pragma unroll
        for (int s = 0; s < 4; ++s) {
            float4 a = *reinterpret_cast<const float4*>(zp + 32 * s);
            float4 b = *reinterpret_cast<const float4*>(zp + 32 * s + 4);
            *reinterpret_cast<float4*>(op + 32 * s) =
                make_float4(a.x - r[s][0], a.y - r[s][1],
                            a.z - r[s][2], a.w - r[s][3]);
            *reinterpret_cast<float4*>(op + 32 * s + 4) =
                make_float4(b.x - r[s][4], b.y - r[s][5],
                            b.z - r[s][6], b.w - r[s][7]);
        }
    }

    // ---- loss reduction ----
    for (int off = 32; off > 0; off >>= 1)
        lsum += __shfl_down(lsum, off, 64);
    if (lane == 0) s_wsum[wid] = lsum;
    __syncthreads();
    if (tid == 0) {
        double t = 0.0;
#pragma unroll
        for (int w = 0; w < 8; ++w) t += s_wsum[w];
        atomicAdd(loss_acc, t);
    }
}

__global__ void rvq_finalize_kernel(const double* __restrict__ loss_acc,
                                    float* __restrict__ out_loss) {
    out_loss[0] = (float)(1.25 * loss_acc[0] / (double)Q_ELEMS);
}

extern "C" void kernel_launch(void* const* d_in, const int* in_sizes, int n_in,
                              void* d_out, int out_size, void* d_ws, size_t ws_size,
                              hipStream_t stream) {
    const float* z  = (const float*)d_in[0];
    const float* cb = (const float*)d_in[1];

    float* out_q    = (float*)d_out;
    float* out_idx  = out_q + Q_ELEMS;
    float* out_loss = out_idx + I_ELEMS;

    double* loss_acc = (double*)d_ws;
    float*  esq      = (float*)((char*)d_ws + 256);              // 8 KB
    bf16x8* g_img    = (bf16x8*)((char*)d_ws + 65536);           // 1 MB
    float*  cbT      = (float*)((char*)d_ws + 65536 + 1048576);  // 1 MB

    hipMemsetAsync(loss_acc, 0, sizeof(double), stream);
    rvq_esq_kernel<<<(NUM_CB * CB_SIZE + 255) / 256, 256, 0, stream>>>(cb, esq);
    rvq_split_kernel<<<(NUM_CB * CB_SIZE * 16 + 255) / 256, 256, 0, stream>>>(
        cb, g_img);
    rvq_transpose_kernel<<<(NUM_CB * DIM * CB_SIZE + 255) / 256, 256, 0,
                           stream>>>(cb, cbT);
    rvq_mfma_kernel<<<BT / 128, 512, 0, stream>>>(z, cb, cbT, esq, g_img,
                                                  out_q, out_idx, loss_acc);
    rvq_finalize_kernel<<<1, 1, 0, stream>>>(loss_acc, out_loss);
}

// Round 14
// 917.981 us; speedup vs baseline: 3.6922x; 3.6922x over previous
//
#include <hip/hip_runtime.h>
#include <hip/hip_bf16.h>
#include <math.h>
#include <float.h>

#define NUM_CB 8
#define CB_SIZE 256
#define DIM 128
#define BT (16 * 16384)                  // 262144 tokens
#define Q_ELEMS ((size_t)BT * DIM)       // 33554432
#define I_ELEMS ((size_t)BT * NUM_CB)    // 2097152

#define TC 64                            // candidates per streamed tile
#define TILES_PER_CB (CB_SIZE / TC)      // 4
#define TILE_BYTES 32768                 // 2 planes x 64 cand x 16 slots x 16B

// Pass-A ambiguity margin (validated rounds 6-12). Do not shrink.
#define MARGIN_A 1.5e-4f

typedef short  bf16x8 __attribute__((ext_vector_type(8)));
typedef float  f32x4  __attribute__((ext_vector_type(4)));

__device__ __forceinline__ unsigned short bf16_rne(float f) {
    unsigned int u = __float_as_uint(f);
    u = u + 0x7FFFu + ((u >> 16) & 1u);
    return (unsigned short)(u >> 16);
}
__device__ __forceinline__ float bf16_tof(unsigned short h) {
    return __uint_as_float(((unsigned int)h) << 16);
}
// Fast HW split helpers (any deterministic split is covered by MARGIN_A).
__device__ __forceinline__ unsigned short f2bf(float f) {
    __hip_bfloat16 h = __float2bfloat16(f);
    return *reinterpret_cast<unsigned short*>(&h);
}

// ---------------------------------------------------------------------------
// VALIDATED np emulation (rounds 6-12): pairwise-8 sum-of-squares, no FMA.
// ---------------------------------------------------------------------------
__device__ __forceinline__ float np_sum_sq_128(const float* a) {
#pragma clang fp contract(off)
    float r0 = 0.f, r1 = 0.f, r2 = 0.f, r3 = 0.f,
          r4 = 0.f, r5 = 0.f, r6 = 0.f, r7 = 0.f;
#pragma unroll
    for (int i = 0; i < DIM; i += 8) {
        r0 = r0 + a[i + 0] * a[i + 0];
        r1 = r1 + a[i + 1] * a[i + 1];
        r2 = r2 + a[i + 2] * a[i + 2];
        r3 = r3 + a[i + 3] * a[i + 3];
        r4 = r4 + a[i + 4] * a[i + 4];
        r5 = r5 + a[i + 5] * a[i + 5];
        r6 = r6 + a[i + 6] * a[i + 6];
        r7 = r7 + a[i + 7] * a[i + 7];
    }
    return ((r0 + r1) + (r2 + r3)) + ((r4 + r5) + (r6 + r7));
}

__global__ void rvq_esq_kernel(const float* __restrict__ cb,
                               float* __restrict__ esq) {
    int i = blockIdx.x * blockDim.x + threadIdx.x;   // 0 .. 2047
    if (i >= NUM_CB * CB_SIZE) return;
    esq[i] = np_sum_sq_128(cb + (size_t)i * DIM);
}

// Transposed f32 codebook for coalesced Pass-B reads: cbT[k][d][c]
__global__ void rvq_transpose_kernel(const float* __restrict__ cb,
                                     float* __restrict__ cbT) {
    int idx = blockIdx.x * blockDim.x + threadIdx.x;   // 0 .. 262143
    if (idx >= NUM_CB * DIM * CB_SIZE) return;
    int c = idx & (CB_SIZE - 1);
    int d = (idx >> 8) & (DIM - 1);
    int k = idx >> 15;
    cbT[idx] = cb[((size_t)(k * CB_SIZE + c)) * DIM + d];
}

// ---------------------------------------------------------------------------
// Precompute merged bf16 hi|lo image in the swizzled LDS layout (validated):
// img[t*2048 + plane*1024 + cand*16 + (slot ^ (cand&15))], t = k*4 + T,
// codeword = t*64 + cand.
// ---------------------------------------------------------------------------
__global__ void rvq_split_kernel(const float* __restrict__ cb,
                                 bf16x8* __restrict__ g_img) {
    int idx = blockIdx.x * blockDim.x + threadIdx.x;   // 0 .. 32767
    if (idx >= NUM_CB * CB_SIZE * 16) return;
    int slot = idx & 15;
    int cand = (idx >> 4) & (TC - 1);
    int t    = idx >> 10;                 // 0..31
    const float* src = cb + ((size_t)t * TC + cand) * DIM + slot * 8;
    float4 a = *reinterpret_cast<const float4*>(src);
    float4 b = *reinterpret_cast<const float4*>(src + 4);
    float e[8] = {a.x, a.y, a.z, a.w, b.x, b.y, b.z, b.w};
    bf16x8 eh, el;
#pragma unroll
    for (int i = 0; i < 8; ++i) {
        unsigned short h = bf16_rne(e[i]);
        float rem = e[i] - bf16_tof(h);
        eh[i] = (short)h;
        el[i] = (short)bf16_rne(rem);
    }
    int ds = slot ^ (cand & 15);
    g_img[(size_t)t * 2048 + cand * 16 + ds]        = eh;
    g_img[(size_t)t * 2048 + 1024 + cand * 16 + ds] = el;
}

// DMA one 32KB tile into LDS buffer: 4 x global_load_lds(16B) per wave (8 wv).
__device__ __forceinline__ void stage_tile(const bf16x8* __restrict__ g_img,
                                           bf16x8 (*s_buf)[2048],
                                           int t, int nb, int wid, int lane) {
    const char* gt = (const char*)g_img + (size_t)t * TILE_BYTES
                     + wid * 4096 + lane * 16;
    const char* lb = (const char*)(&s_buf[nb][0]) + wid * 4096;  // wave-uniform
#pragma unroll
    for (int c = 0; c < 4; ++c) {
        __builtin_amdgcn_global_load_lds(
            (const __attribute__((address_space(1))) unsigned int*)(gt + c * 1024),
            (__attribute__((address_space(3))) unsigned int*)(lb + c * 1024),
            16, 0, 0);
    }
}

// ---------------------------------------------------------------------------
// Main fused kernel: 128 tokens/block (8 waves x 16), residual in VGPRs.
// SWAPPED MFMA: mfma(E, R) -> lane holds its OWN token's candidate scores
// (D col = token = lane&15, D row = candidate = 4*lq + j). Per-lane top-2,
// 2-step cross-lq reduce, no LDS selection traffic.
// __launch_bounds__(512, 2): 128-VGPR cap -- NO SPILL (r13's (512,4) forced a
// 64-VGPR clamp and spilled the residual to scratch: 9.4 GB HBM traffic).
// ---------------------------------------------------------------------------
__global__ __launch_bounds__(512, 2) void rvq_mfma_kernel(
    const float* __restrict__ z,
    const float* __restrict__ cb,
    const float* __restrict__ cbT,
    const float* __restrict__ esq,
    const bf16x8* __restrict__ g_img,
    float* __restrict__ out_q,
    float* __restrict__ out_idx,
    double* __restrict__ loss_acc) {

    __shared__ bf16x8 s_buf[2][2048];                // 2 x 32KB double buffer
    __shared__ __align__(16) float s_rbuf[8][DIM];   // per-wave passB residual
    __shared__ double s_wsum[8];

    const int tid  = threadIdx.x;
    const int wid  = tid >> 6;
    const int lane = tid & 63;
    const int lrow = lane & 15;       // token-in-wave (B col / D col)
    const int lq   = lane >> 4;       // k-chunk group / D row group
    const int tokw = blockIdx.x * 128 + wid * 16;
    const int tok  = tokw + lrow;

    // ---- residual chunks: r[s][i] = z[tok][32s + 8lq + i] ----
    float r[4][8];
    {
        const float* zp = z + (size_t)tok * DIM + 8 * lq;
#pragma unroll
        for (int s = 0; s < 4; ++s) {
            float4 a = *reinterpret_cast<const float4*>(zp + 32 * s);
            float4 b = *reinterpret_cast<const float4*>(zp + 32 * s + 4);
            r[s][0] = a.x; r[s][1] = a.y; r[s][2] = a.z; r[s][3] = a.w;
            r[s][4] = b.x; r[s][5] = b.y; r[s][6] = b.z; r[s][7] = b.w;
        }
    }

    // ---- fast bf16 hi/mid split (HW RNE casts) ----
    bf16x8 ah[4], am[4];
#pragma unroll
    for (int s = 0; s < 4; ++s)
#pragma unroll
        for (int i = 0; i < 8; ++i) {
            unsigned short h = f2bf(r[s][i]);
            float rem = r[s][i] - bf16_tof(h);
            ah[s][i] = (short)h;
            am[s][i] = (short)f2bf(rem);
        }

    double lsum = 0.0;

    // prologue: stage tile 0
    stage_tile(g_img, s_buf, 0, 0, wid, lane);
    asm volatile("s_waitcnt vmcnt(0)" ::: "memory");
    __syncthreads();

    for (int k = 0; k < NUM_CB; ++k) {
        const float* esqk = esq + k * CB_SIZE;
        const float* cbk  = cb  + (size_t)k * CB_SIZE * DIM;
        const float* cbTk = cbT + (size_t)k * DIM * CB_SIZE + lane;

        float m1 = FLT_MAX, m2 = FLT_MAX;
        int   i1 = 0x7fffffff;

#pragma unroll
        for (int T = 0; T < TILES_PER_CB; ++T) {
            const int t  = k * TILES_PER_CB + T;
            const int nb = T & 1;
            if (k < NUM_CB - 1 || T < TILES_PER_CB - 1)
                stage_tile(g_img, s_buf, t + 1, nb ^ 1, wid, lane);

#pragma unroll
            for (int ctl = 0; ctl < 4; ++ctl) {   // 16-candidate column tiles
                const int ctg  = T * 4 + ctl;     // global ct 0..15
                const int base = (ctl * 16 + lrow) * 16;
                bf16x8 bh[4], bl[4];
#pragma unroll
                for (int s = 0; s < 4; ++s) {
                    int ls = (4 * s + lq) ^ lrow;
                    bh[s] = s_buf[nb][base + ls];
                    bl[s] = s_buf[nb][1024 + base + ls];
                }
                f32x4 acc0 = {0.f, 0.f, 0.f, 0.f};
                f32x4 acc1 = {0.f, 0.f, 0.f, 0.f};
                // SWAPPED: A = codebook frag, B = residual frag
                acc0 = __builtin_amdgcn_mfma_f32_16x16x32_bf16(bh[0], ah[0], acc0, 0, 0, 0);
                acc0 = __builtin_amdgcn_mfma_f32_16x16x32_bf16(bh[1], ah[1], acc0, 0, 0, 0);
                acc1 = __builtin_amdgcn_mfma_f32_16x16x32_bf16(bh[2], ah[2], acc1, 0, 0, 0);
                acc1 = __builtin_amdgcn_mfma_f32_16x16x32_bf16(bh[3], ah[3], acc1, 0, 0, 0);
                acc0 = __builtin_amdgcn_mfma_f32_16x16x32_bf16(bh[0], am[0], acc0, 0, 0, 0);
                acc0 = __builtin_amdgcn_mfma_f32_16x16x32_bf16(bh[1], am[1], acc0, 0, 0, 0);
                acc1 = __builtin_amdgcn_mfma_f32_16x16x32_bf16(bh[2], am[2], acc1, 0, 0, 0);
                acc1 = __builtin_amdgcn_mfma_f32_16x16x32_bf16(bh[3], am[3], acc1, 0, 0, 0);
                acc0 = __builtin_amdgcn_mfma_f32_16x16x32_bf16(bl[0], ah[0], acc0, 0, 0, 0);
                acc0 = __builtin_amdgcn_mfma_f32_16x16x32_bf16(bl[1], ah[1], acc0, 0, 0, 0);
                acc1 = __builtin_amdgcn_mfma_f32_16x16x32_bf16(bl[2], ah[2], acc1, 0, 0, 0);
                acc1 = __builtin_amdgcn_mfma_f32_16x16x32_bf16(bl[3], ah[3], acc1, 0, 0, 0);

                // scores: candidate c = ctg*16 + 4*lq + j for THIS lane's token
                float4 ev = *reinterpret_cast<const float4*>(
                    esqk + ctg * 16 + 4 * lq);
                const float es[4] = {ev.x, ev.y, ev.z, ev.w};
                const int cb0 = ctg * 16 + 4 * lq;
#pragma unroll
                for (int j = 0; j < 4; ++j) {
                    float s = fmaf(-2.0f, acc0[j] + acc1[j], es[j]);
                    m2 = fminf(m2, fmaxf(m1, s));
                    if (s < m1) { m1 = s; i1 = cb0 + j; }   // ascending c order
                }
            }

            if (T == TILES_PER_CB - 1) {
                // ============== per-codebook epilogue (wave-internal) ======
                // cross-lq top-2 lexicographic reduce (2 butterfly steps)
#pragma unroll
                for (int d = 16; d < 64; d <<= 1) {
                    float om1 = __shfl_xor(m1, d);
                    float om2 = __shfl_xor(m2, d);
                    int   oi1 = __shfl_xor(i1, d);
                    bool ow = (om1 < m1) || (om1 == m1 && oi1 < i1);
                    float lo = ow ? m1 : om1;
                    m1 = ow ? om1 : m1;
                    i1 = ow ? oi1 : i1;
                    m2 = fminf(fminf(m2, om2), lo);
                }
                int cmin = i1;

                // Pass B (rare): exact np argmin, coalesced cbT (validated)
                bool amb = !(m2 - m1 > MARGIN_A);
                unsigned long long mask = __ballot(amb && lane < 16);
                while (mask) {
                    int srct = __ffsll(mask) - 1;
                    mask &= mask - 1;
                    if (lrow == srct) {
#pragma unroll
                        for (int s = 0; s < 4; ++s) {
                            float4* dst = reinterpret_cast<float4*>(
                                &s_rbuf[wid][32 * s + 8 * lq]);
                            dst[0] = make_float4(r[s][0], r[s][1], r[s][2], r[s][3]);
                            dst[1] = make_float4(r[s][4], r[s][5], r[s][6], r[s][7]);
                        }
                    }
                    asm volatile("s_waitcnt lgkmcnt(0)" ::: "memory");
                    float xs = 0.f;
                    if (lane == 0) xs = np_sum_sq_128(&s_rbuf[wid][0]);
                    xs = __shfl(xs, 0);

                    const float* rb = &s_rbuf[wid][0];
                    float a0 = 0.f, a1 = 0.f, a2 = 0.f, a3 = 0.f;
#pragma unroll 8
                    for (int d = 0; d < DIM; ++d) {
                        float rv = rb[d];
                        const float* row = cbTk + (size_t)d * CB_SIZE;
                        a0 = fmaf(rv, row[0],   a0);
                        a1 = fmaf(rv, row[64],  a1);
                        a2 = fmaf(rv, row[128], a2);
                        a3 = fmaf(rv, row[192], a3);
                    }
                    float dd0, dd1, dd2, dd3;
                    {
#pragma clang fp contract(off)
                        float S0 = xs + esqk[lane];
                        float S1 = xs + esqk[lane + 64];
                        float S2 = xs + esqk[lane + 128];
                        float S3 = xs + esqk[lane + 192];
                        dd0 = S0 - 2.0f * a0;
                        dd1 = S1 - 2.0f * a1;
                        dd2 = S2 - 2.0f * a2;
                        dd3 = S3 - 2.0f * a3;
                    }
                    float bd = dd0; int bc = lane;
                    if (dd1 < bd) { bd = dd1; bc = lane + 64; }
                    if (dd2 < bd) { bd = dd2; bc = lane + 128; }
                    if (dd3 < bd) { bd = dd3; bc = lane + 192; }
#pragma unroll
                    for (int d = 1; d < 64; d <<= 1) {
                        float od = __shfl_xor(bd, d);
                        int   oc = __shfl_xor(bc, d);
                        if (od < bd || (od == bd && oc < bc)) { bd = od; bc = oc; }
                    }
                    if (lrow == srct) cmin = bc;   // all lanes have (bd,bc)
                }

                if (lane < 16)    // lane==lrow owner copy
                    out_idx[(size_t)(tokw + lane) * NUM_CB + k] = (float)cmin;

                // residual update + loss
                const float* ep = cbk + (size_t)cmin * DIM + 8 * lq;
                float l0 = 0.f, l1 = 0.f, l2 = 0.f, l3 = 0.f;
#pragma unroll
                for (int s = 0; s < 4; ++s) {
                    float4 ev0 = *reinterpret_cast<const float4*>(ep + 32 * s);
                    float4 ev1 = *reinterpret_cast<const float4*>(ep + 32 * s + 4);
                    float d0 = ev0.x - r[s][0], d1 = ev0.y - r[s][1];
                    float d2 = ev0.z - r[s][2], d3 = ev0.w - r[s][3];
                    float d4 = ev1.x - r[s][4], d5 = ev1.y - r[s][5];
                    float d6 = ev1.z - r[s][6], d7 = ev1.w - r[s][7];
                    l0 = fmaf(d0, d0, l0); l1 = fmaf(d1, d1, l1);
                    l2 = fmaf(d2, d2, l2); l3 = fmaf(d3, d3, l3);
                    l0 = fmaf(d4, d4, l0); l1 = fmaf(d5, d5, l1);
                    l2 = fmaf(d6, d6, l2); l3 = fmaf(d7, d7, l3);
                    r[s][0] -= ev0.x; r[s][1] -= ev0.y; r[s][2] -= ev0.z; r[s][3] -= ev0.w;
                    r[s][4] -= ev1.x; r[s][5] -= ev1.y; r[s][6] -= ev1.z; r[s][7] -= ev1.w;
                }
                lsum += (double)((l0 + l1) + (l2 + l3));

                if (k < NUM_CB - 1) {   // fast re-split for next codebook
#pragma unroll
                    for (int s = 0; s < 4; ++s)
#pragma unroll
                        for (int i = 0; i < 8; ++i) {
                            unsigned short h = f2bf(r[s][i]);
                            float rem = r[s][i] - bf16_tof(h);
                            ah[s][i] = (short)h;
                            am[s][i] = (short)f2bf(rem);
                        }
                }
                // ============== end epilogue ===============================
            }

            asm volatile("s_waitcnt vmcnt(0)" ::: "memory");  // prefetch landed
            __syncthreads();                                  // buf[nb] free
        }
    }

    // ---- quantized = z - r_final ----
    {
        const float* zp = z + (size_t)tok * DIM + 8 * lq;
        float* op = out_q + (size_t)tok * DIM + 8 * lq;
#pragma unroll
        for (int s = 0; s < 4; ++s) {
            float4 a = *reinterpret_cast<const float4*>(zp + 32 * s);
            float4 b = *reinterpret_cast<const float4*>(zp + 32 * s + 4);
            *reinterpret_cast<float4*>(op + 32 * s) =
                make_float4(a.x - r[s][0], a.y - r[s][1],
                            a.z - r[s][2], a.w - r[s][3]);
            *reinterpret_cast<float4*>(op + 32 * s + 4) =
                make_float4(b.x - r[s][4], b.y - r[s][5],
                            b.z - r[s][6], b.w - r[s][7]);
        }
    }

    // ---- loss reduction ----
    for (int off = 32; off > 0; off >>= 1)
        lsum += __shfl_down(lsum, off, 64);
    if (lane == 0) s_wsum[wid] = lsum;
    __syncthreads();
    if (tid == 0) {
        double t = 0.0;
#pragma unroll
        for (int w = 0; w < 8; ++w) t += s_wsum[w];
        atomicAdd(loss_acc, t);
    }
}

__global__ void rvq_finalize_kernel(const double* __restrict__ loss_acc,
                                    float* __restrict__ out_loss) {
    out_loss[0] = (float)(1.25 * loss_acc[0] / (double)Q_ELEMS);
}

extern "C" void kernel_launch(void* const* d_in, const int* in_sizes, int n_in,
                              void* d_out, int out_size, void* d_ws, size_t ws_size,
                              hipStream_t stream) {
    const float* z  = (const float*)d_in[0];
    const float* cb = (const float*)d_in[1];

    float* out_q    = (float*)d_out;
    float* out_idx  = out_q + Q_ELEMS;
    float* out_loss = out_idx + I_ELEMS;

    double* loss_acc = (double*)d_ws;
    float*  esq      = (float*)((char*)d_ws + 256);              // 8 KB
    bf16x8* g_img    = (bf16x8*)((char*)d_ws + 65536);           // 1 MB
    float*  cbT      = (float*)((char*)d_ws + 65536 + 1048576);  // 1 MB

    hipMemsetAsync(loss_acc, 0, sizeof(double), stream);
    rvq_esq_kernel<<<(NUM_CB * CB_SIZE + 255) / 256, 256, 0, stream>>>(cb, esq);
    rvq_split_kernel<<<(NUM_CB * CB_SIZE * 16 + 255) / 256, 256, 0, stream>>>(
        cb, g_img);
    rvq_transpose_kernel<<<(NUM_CB * DIM * CB_SIZE + 255) / 256, 256, 0,
                           stream>>>(cb, cbT);
    rvq_mfma_kernel<<<BT / 128, 512, 0, stream>>>(z, cb, cbT, esq, g_img,
                                                  out_q, out_idx, loss_acc);
    rvq_finalize_kernel<<<1, 1, 0, stream>>>(loss_acc, out_loss);
}